// Round 15
// baseline (1063.786 us; speedup 1.0000x reference)
//
#include <hip/hip_runtime.h>

// BiLSTM-CRF on MI355X — round 15: no-k-split scan at 1 wave/SIMD.
// LDS (148KB) already forces 1 block/CU, so use 256-thread blocks (4 waves,
// 1/SIMD -> 512-reg cap; m08: no spill through 450): each thread owns one j
// COMPLETELY: 96 kk in registers (384 VGPR/AGPR) + 32 kk in a 128 KB LDS
// slab. Deletes the k-split partial-reduce (plds + barrier); h double-buffered
// (write s+1 buffer while s buffer is read) -> ONE barrier per step.
// Non-scan kernels unchanged from R13/R14.
//
// ws layout: X4 (67108864) | WTH (1048576) | FT (786432) | WpH (12288) |
//            H u16 (16777216)  = 85.7 MB total.
// Output (float32): d_out[0:16384] = paths (floats, -1 past length), [16384:16448] = best_score.

#define NB 64
#define NT 256
#define NKTAG 12
#define START_TAG 10
#define KK_SLAB3 32   // LDS slab kk -> 131072 B
#define KK_REG3 96    // register kk per thread (96 x uint4 = 384 regs)

typedef unsigned short u16;
typedef _Float16 half2v __attribute__((ext_vector_type(2)));
typedef _Float16 half8 __attribute__((ext_vector_type(8)));
typedef float f32x4 __attribute__((ext_vector_type(4)));

__device__ __forceinline__ float b2f(u16 u) {
  union { unsigned int i; float f; } v; v.i = ((unsigned int)u) << 16; return v.f;
}
__device__ __forceinline__ u16 f2b(float f) {
  union { float f; unsigned int i; } v; v.f = f;
  unsigned int r = v.i + 0x7FFFu + ((v.i >> 16) & 1u);
  return (u16)(r >> 16);
}
__device__ __forceinline__ u16 f2h(float f) {
  union { _Float16 h; u16 u; } v; v.h = (_Float16)f; return v.u;
}
__device__ __forceinline__ unsigned int pkh(float x, float y) {
  return (unsigned int)f2h(x) | ((unsigned int)f2h(y) << 16);
}
__device__ __forceinline__ float fsig(float x) { return 1.0f / (1.0f + __expf(-x)); }
__device__ __forceinline__ float ftanh(float x) { return 2.0f / (1.0f + __expf(-2.0f * x)) - 1.0f; }

__device__ __forceinline__ float dot2h(unsigned int a, unsigned int b, float c) {
#if __has_builtin(__builtin_amdgcn_fdot2)
  union { unsigned int u; half2v h; } va, vb;
  va.u = a; vb.u = b;
  return __builtin_amdgcn_fdot2(va.h, vb.h, c, false);
#else
  float d;
  asm("v_dot2_f32_f16 %0, %1, %2, %3" : "=v"(d) : "v"(a), "v"(b), "v"(c));
  return d;
#endif
}

// ---------------------------------------------------------------- pack_whh (+WpH)
__global__ __launch_bounds__(256) void pack_whh(const float* __restrict__ Whf,
                                                const float* __restrict__ Whb,
                                                const float* __restrict__ Wp,
                                                uint4* __restrict__ WT,
                                                unsigned int* __restrict__ WpH) {
  if (blockIdx.x == 256) {   // WpH: [12][256] packed f16 pairs of Wp[12][512]
    for (int it = 0; it < 12; ++it) {
      int idx = it * 256 + threadIdx.x;
      int k = idx >> 8, cc = idx & 255;
      WpH[idx] = pkh(Wp[(size_t)k * 512 + 2 * cc], Wp[(size_t)k * 512 + 2 * cc + 1]);
    }
    return;
  }
  int gid = blockIdx.x * 256 + threadIdx.x;      // 2*128*256 = 65536
  int d = gid >> 15;
  int rem = gid & 32767;
  int kk = rem >> 8, j = rem & 255;
  const float* W = d ? Whb : Whf;
  int k0 = kk * 2;
  uint4 o;
  o.x = pkh(W[(size_t)j * 256 + k0],         W[(size_t)j * 256 + k0 + 1]);
  o.y = pkh(W[(size_t)(j + 256) * 256 + k0], W[(size_t)(j + 256) * 256 + k0 + 1]);
  o.z = pkh(W[(size_t)(j + 512) * 256 + k0], W[(size_t)(j + 512) * 256 + k0 + 1]);
  o.w = pkh(W[(size_t)(j + 768) * 256 + k0], W[(size_t)(j + 768) * 256 + k0 + 1]);
  WT[gid] = o;
}

// ---------------------------------------------------------------- gemm_x (MFMA)
// (unchanged from round 13, incl. XCD swizzle)
__global__ __launch_bounds__(256) void gemm_x(const int* __restrict__ sent,
                                              const float* __restrict__ emb,
                                              const float* __restrict__ Wf,
                                              const float* __restrict__ Wb,
                                              const float* __restrict__ bihf,
                                              const float* __restrict__ bhhf,
                                              const float* __restrict__ bihb,
                                              const float* __restrict__ bhhb,
                                              u16* __restrict__ X4) {
  __shared__ _Float16 A_lds[128][40];
  __shared__ _Float16 B_lds[64][40];
  __shared__ int tok[128];
  __shared__ u16 Xs[128][80];
  int tid = threadIdx.x;
  int lin = blockIdx.y * 32 + blockIdx.x;
  int swz = (lin & 7) * 512 + (lin >> 3);
  int in = swz & 31;                   // 0..31
  int im = swz >> 5;                   // 0..127
  int d = in >> 4, j0 = (in & 15) * 16;
  if (tid < 128) tok[tid] = sent[im * 128 + tid];

  int w = tid >> 6, l = tid & 63;
  int lrow = l & 15, lk = l >> 4;
  f32x4 acc[2][4];
#pragma unroll
  for (int mt = 0; mt < 2; ++mt)
#pragma unroll
    for (int nt = 0; nt < 4; ++nt) acc[mt][nt] = (f32x4)0.0f;

  int arow = tid >> 1, akh = tid & 1;
  int brow = tid & 63, bkq = tid >> 6;
  int r_w = ((brow >> 4) << 8) + j0 + (brow & 15);   // gate*256 + j
  const float* wrow = (d ? Wb : Wf) + (size_t)r_w * 256;

  for (int kc = 0; kc < 8; ++kc) {
    int k0 = kc * 32;
    __syncthreads();
    {
      const float* ap = emb + (size_t)tok[arow] * 256 + k0 + akh * 16;
#pragma unroll
      for (int q = 0; q < 2; ++q) {
        float4 v0 = *(const float4*)(ap + q * 8);
        float4 v1 = *(const float4*)(ap + q * 8 + 4);
        uint4 pk;
        pk.x = pkh(v0.x, v0.y); pk.y = pkh(v0.z, v0.w);
        pk.z = pkh(v1.x, v1.y); pk.w = pkh(v1.z, v1.w);
        *(uint4*)&A_lds[arow][akh * 16 + q * 8] = pk;
      }
    }
    {
      float4 v0 = *(const float4*)(wrow + k0 + bkq * 8);
      float4 v1 = *(const float4*)(wrow + k0 + bkq * 8 + 4);
      uint4 pk;
      pk.x = pkh(v0.x, v0.y); pk.y = pkh(v0.z, v0.w);
      pk.z = pkh(v1.x, v1.y); pk.w = pkh(v1.z, v1.w);
      *(uint4*)&B_lds[brow][bkq * 8] = pk;
    }
    __syncthreads();
    half8 af[2], bf[4];
#pragma unroll
    for (int mt = 0; mt < 2; ++mt)
      af[mt] = *(const half8*)&A_lds[w * 32 + mt * 16 + lrow][lk * 8];
#pragma unroll
    for (int nt = 0; nt < 4; ++nt)
      bf[nt] = *(const half8*)&B_lds[nt * 16 + lrow][lk * 8];
#pragma unroll
    for (int mt = 0; mt < 2; ++mt)
#pragma unroll
      for (int nt = 0; nt < 4; ++nt)
        acc[mt][nt] = __builtin_amdgcn_mfma_f32_16x16x32_f16(af[mt], bf[nt], acc[mt][nt], 0, 0, 0);
  }
  float bias[4];
#pragma unroll
  for (int nt = 0; nt < 4; ++nt) {
    int rr = nt * 256 + j0 + lrow;
    bias[nt] = d ? (bihb[rr] + bhhb[rr]) : (bihf[rr] + bhhf[rr]);
  }
  __syncthreads();
#pragma unroll
  for (int mt = 0; mt < 2; ++mt)
#pragma unroll
    for (int r = 0; r < 4; ++r) {
      int row = w * 32 + mt * 16 + lk * 4 + r;
      uint2 pk;
      pk.x = (unsigned int)f2b(acc[mt][0][r] + bias[0]) |
             ((unsigned int)f2b(acc[mt][1][r] + bias[1]) << 16);
      pk.y = (unsigned int)f2b(acc[mt][2][r] + bias[2]) |
             ((unsigned int)f2b(acc[mt][3][r] + bias[3]) << 16);
      *(uint2*)&Xs[row][lrow * 4] = pk;
    }
  __syncthreads();
  int frow = tid >> 1, fh = tid & 1;
  int i = im * 128 + frow;
  int bb = i >> 8, tt = i & 255;
  size_t base = (((size_t)d * NT + tt) * NB + bb) * 1024 + (size_t)j0 * 4 + fh * 32;
#pragma unroll
  for (int q = 0; q < 4; ++q)
    *(uint4*)&X4[base + q * 8] = *(const uint4*)&Xs[frow][fh * 32 + q * 8];
}

// ---------------------------------------------------------------- lstm_scan
// 128 blocks x 256 threads; thread jj owns hidden unit jj completely.
// kk 0..31 from 128 KB LDS slab, kk 32..127 from wreg[96] (static unroll).
// h double-buffered in LDS (read buf s&1, write buf (s+1)&1) -> 1 barrier/step.
__global__ __launch_bounds__(256, 1) void lstm_scan(const uint4* __restrict__ WT,
                                                    const ushort4* __restrict__ X4,
                                                    const float* __restrict__ h0,
                                                    const float* __restrict__ c0,
                                                    u16* __restrict__ H) {
  int d = blockIdx.x >> 6, b = blockIdx.x & 63;
  int jj = threadIdx.x;
  __shared__ uint4 wlds[KK_SLAB3 * 256];   // 131072 B slab: kk 0..31
  __shared__ uint4 hbuf2[2][32];           // double-buffered packed f16 h pairs
  const uint4* Ws = WT + (size_t)d * 32768;   // [kk][j]
  for (int e = jj; e < KK_SLAB3 * 256; e += 256) wlds[e] = Ws[e];
  uint4 wreg[KK_REG3];
#pragma unroll
  for (int r = 0; r < KK_REG3; ++r)
    wreg[r] = Ws[(size_t)(KK_SLAB3 + r) * 256 + jj];
  float c = c0[((size_t)d * NB + b) * 256 + jj];
  ((u16*)hbuf2[0])[jj] = f2h(h0[((size_t)d * NB + b) * 256 + jj]);
  __syncthreads();
  for (int s = 0; s < NT; ++s) {
    int t = d ? (NT - 1 - s) : s;
    ushort4 xg = X4[(((size_t)d * NT + t) * NB + b) * 256 + jj];
    const uint4* hb = hbuf2[s & 1];
    float ai = 0.f, af = 0.f, ag = 0.f, ao = 0.f;
#pragma unroll
    for (int q = 0; q < 32; ++q) {
      uint4 h4 = hb[q];                          // uniform -> broadcast b128
      unsigned int hp[4] = {h4.x, h4.y, h4.z, h4.w};
#pragma unroll
      for (int e = 0; e < 4; ++e) {
        int kk = q * 4 + e;                      // compile-time constant
        uint4 wv;
        if (kk < KK_SLAB3) wv = wlds[(kk << 8) | jj];
        else               wv = wreg[kk - KK_SLAB3];
        ai = dot2h(wv.x, hp[e], ai); af = dot2h(wv.y, hp[e], af);
        ag = dot2h(wv.z, hp[e], ag); ao = dot2h(wv.w, hp[e], ao);
      }
    }
    ai += b2f(xg.x); af += b2f(xg.y); ag += b2f(xg.z); ao += b2f(xg.w);
    float ii = fsig(ai), ff = fsig(af), gg = ftanh(ag), oo = fsig(ao);
    c = ff * c + ii * gg;
    float h = oo * ftanh(c);
    u16 hu = f2h(h);
    ((u16*)hbuf2[(s + 1) & 1])[jj] = hu;
    H[(((size_t)d * NB + b) * NT + t) * 256 + jj] = hu;
    __syncthreads();                   // new h buffer complete before next step
  }
}

// ---------------------------------------------------------------- feats
// (unchanged from round 13)
__global__ __launch_bounds__(384) void feats_kernel(const u16* __restrict__ H,
                                                    const unsigned int* __restrict__ WpH,
                                                    const float* __restrict__ bp,
                                                    float* __restrict__ FT) {
  __shared__ uint4 hbuf[32][65];
  __shared__ uint4 wbuf[64][12];
  int tid = threadIdx.x;
  int i0 = blockIdx.x * 32;
  for (int idx = tid; idx < 768; idx += 384) {
    int it = idx / 12, k = idx - it * 12;
    wbuf[it][k] = ((const uint4*)WpH)[k * 64 + it];
  }
  for (int idx = tid; idx < 2048; idx += 384) {
    int row = idx >> 6, c4 = idx & 63;
    int i = i0 + row;
    int b = i >> 8, t = i & 255;
    int dd = c4 >> 5, cc = c4 & 31;
    const uint4* hpg = (const uint4*)(H + (((size_t)dd * NB + b) * NT + t) * 256);
    hbuf[row][c4] = hpg[cc];
  }
  __syncthreads();
  int row = tid / 12, k = tid - row * 12;
  float s0 = 0.f, s1 = 0.f, s2 = 0.f, s3 = 0.f;
#pragma unroll 8
  for (int it = 0; it < 64; ++it) {
    uint4 h4 = hbuf[row][it];
    uint4 w4 = wbuf[it][k];
    s0 = dot2h(h4.x, w4.x, s0); s1 = dot2h(h4.y, w4.y, s1);
    s2 = dot2h(h4.z, w4.z, s2); s3 = dot2h(h4.w, w4.w, s3);
  }
  int i = i0 + row;
  FT[(size_t)i * NKTAG + k] = (s0 + s1) + (s2 + s3) + bp[k];
}

// ---------------------------------------------------------------- viterbi
// (unchanged from round 13, incl. FT prefetch)
__global__ __launch_bounds__(64) void viterbi_kernel(const float* __restrict__ FT,
                                                     const float* __restrict__ trans,
                                                     const int* __restrict__ sent,
                                                     float* __restrict__ out) {
  int b = blockIdx.x, tid = threadIdx.x;
  __shared__ float trans_s[12][12];
  __shared__ float s_s[12];
  __shared__ unsigned char bp_s[256][12];
  __shared__ int path_s[256];
  for (int idx = tid; idx < 144; idx += 64) trans_s[idx / 12][idx % 12] = trans[idx];
  int cnt = 0;
#pragma unroll
  for (int q = 0; q < 4; ++q) cnt += (sent[b * NT + q * 64 + tid] > 0) ? 1 : 0;
  for (int off = 32; off; off >>= 1) cnt += __shfl_down(cnt, off);
  int len = __shfl(cnt, 0);
  if (tid < 12) s_s[tid] = (tid == START_TAG) ? 0.f : -10000.f;
  float f_next = (tid < 12) ? FT[((size_t)b * NT) * NKTAG + tid] : 0.f;
  __syncthreads();
  for (int t = 0; t < NT; ++t) {
    float best = 0.f, f = f_next;
    int barg = 0;
    if (t + 1 < NT && tid < 12)
      f_next = FT[((size_t)b * NT + t + 1) * NKTAG + tid];  // prefetch, state-indep
    if (tid < 12) {
      best = s_s[0] + trans_s[tid][0];
      barg = 0;
#pragma unroll
      for (int fr = 1; fr < 12; ++fr) {
        float v = s_s[fr] + trans_s[tid][fr];
        if (v > best) { best = v; barg = fr; }  // strict > keeps first (jnp.argmax)
      }
    }
    __syncthreads();
    if (tid < 12) {
      s_s[tid] = best + f;
      bp_s[t][tid] = (unsigned char)barg;
    }
    __syncthreads();
  }
  if (tid == 0) {
    float bs = s_s[0];
    int bt = 0;
    for (int k = 1; k < 12; ++k)
      if (s_s[k] > bs) { bs = s_s[k]; bt = k; }
    out[NB * NT + b] = bs;
    int x = bt;
    for (int tt = NT - 1; tt >= 0; --tt) {
      path_s[tt] = x;
      int nxt = bp_s[tt][x];
      if (tt < len) x = nxt;
    }
  }
  __syncthreads();
#pragma unroll
  for (int q = 0; q < 4; ++q) {
    int t = q * 64 + tid;
    out[b * NT + t] = (t < len) ? (float)path_s[t] : -1.0f;
  }
}

// ---------------------------------------------------------------- launch
extern "C" void kernel_launch(void* const* d_in, const int* in_sizes, int n_in,
                              void* d_out, int out_size, void* d_ws, size_t ws_size,
                              hipStream_t stream) {
  (void)in_sizes; (void)n_in; (void)out_size; (void)ws_size;
  const int*   sent  = (const int*)d_in[0];
  const float* emb   = (const float*)d_in[2];
  const float* Wih_f = (const float*)d_in[3];
  const float* Whh_f = (const float*)d_in[4];
  const float* bih_f = (const float*)d_in[5];
  const float* bhh_f = (const float*)d_in[6];
  const float* Wih_b = (const float*)d_in[7];
  const float* Whh_b = (const float*)d_in[8];
  const float* bih_b = (const float*)d_in[9];
  const float* bhh_b = (const float*)d_in[10];
  const float* Wp    = (const float*)d_in[11];
  const float* bp    = (const float*)d_in[12];
  const float* trans = (const float*)d_in[13];
  const float* h0    = (const float*)d_in[14];
  const float* c0    = (const float*)d_in[15];
  float* out = (float*)d_out;

  char* w = (char*)d_ws;
  u16*   X4  = (u16*)w;                                      // 67108864 B
  uint4* WTH = (uint4*)(w + 67108864);                       //  1048576 B
  float* FT  = (float*)(w + 68157440);                       //   786432 B
  unsigned int* WpH = (unsigned int*)(w + 68943872);         //    12288 B
  u16*   H   = (u16*)(w + 68956160);                         // 16777216 B

  pack_whh<<<dim3(257), dim3(256), 0, stream>>>(Whh_f, Whh_b, Wp, WTH, WpH);
  gemm_x<<<dim3(32, 128), dim3(256), 0, stream>>>(sent, emb, Wih_f, Wih_b,
                                                  bih_f, bhh_f, bih_b, bhh_b, X4);
  lstm_scan<<<dim3(128), dim3(256), 0, stream>>>(WTH, (const ushort4*)X4, h0, c0, H);
  feats_kernel<<<dim3(512), dim3(384), 0, stream>>>(H, WpH, bp, FT);
  viterbi_kernel<<<dim3(64), dim3(64), 0, stream>>>(FT, trans, sent, out);
}

// Round 16
// 559.037 us; speedup vs baseline: 1.9029x; 1.9029x over previous
//
#include <hip/hip_runtime.h>

// BiLSTM-CRF on MI355X — round 16: R14 scan (proven 417us) + two cuts:
//  * slab/reg rebalance 18/46 -> 8/56 (224 AGPR < 256 cap; -10 lane-varying
//    slab b128 reads/thread/step ~ -960 cy/CU). Same kk order -> bit-identical.
//  * lgkm-only barriers: __syncthreads drains vmcnt(0) (the H global store +
//    X4 load) every step; loop ordering only needs LDS visibility ->
//    s_waitcnt lgkmcnt(0) + raw s_barrier. (R15's 96-reg full residency
//    refuted: allocator spilled at 1 wave/SIMD -> 910us.)
// Non-scan kernels unchanged from R13.
//
// ws layout: X4 (67108864) | WTH (1048576) | FT (786432) | WpH (12288) |
//            H u16 (16777216)  = 85.7 MB total.
// Output (float32): d_out[0:16384] = paths (floats, -1 past length), [16384:16448] = best_score.

#define NB 64
#define NT 256
#define NKTAG 12
#define START_TAG 10
#define KK_SLAB2 8    // per-group LDS-slab kk (16 total = 65536 B)
#define KK_REG2 56    // per-group register kk (56 x uint4 = 224 regs)

typedef unsigned short u16;
typedef _Float16 half2v __attribute__((ext_vector_type(2)));
typedef _Float16 half8 __attribute__((ext_vector_type(8)));
typedef float f32x4 __attribute__((ext_vector_type(4)));

__device__ __forceinline__ float b2f(u16 u) {
  union { unsigned int i; float f; } v; v.i = ((unsigned int)u) << 16; return v.f;
}
__device__ __forceinline__ u16 f2b(float f) {
  union { float f; unsigned int i; } v; v.f = f;
  unsigned int r = v.i + 0x7FFFu + ((v.i >> 16) & 1u);
  return (u16)(r >> 16);
}
__device__ __forceinline__ u16 f2h(float f) {
  union { _Float16 h; u16 u; } v; v.h = (_Float16)f; return v.u;
}
__device__ __forceinline__ unsigned int pkh(float x, float y) {
  return (unsigned int)f2h(x) | ((unsigned int)f2h(y) << 16);
}
__device__ __forceinline__ float fsig(float x) { return 1.0f / (1.0f + __expf(-x)); }
__device__ __forceinline__ float ftanh(float x) { return 2.0f / (1.0f + __expf(-2.0f * x)) - 1.0f; }

__device__ __forceinline__ float dot2h(unsigned int a, unsigned int b, float c) {
#if __has_builtin(__builtin_amdgcn_fdot2)
  union { unsigned int u; half2v h; } va, vb;
  va.u = a; vb.u = b;
  return __builtin_amdgcn_fdot2(va.h, vb.h, c, false);
#else
  float d;
  asm("v_dot2_f32_f16 %0, %1, %2, %3" : "=v"(d) : "v"(a), "v"(b), "v"(c));
  return d;
#endif
}

// LDS-only barrier: wait LDS ops, then raw s_barrier (no vmcnt drain --
// the per-step H store / X4 load are thread-private and tracked at use).
__device__ __forceinline__ void barrier_lds() {
  asm volatile("s_waitcnt lgkmcnt(0)" ::: "memory");
  __builtin_amdgcn_s_barrier();
}

// ---------------------------------------------------------------- pack_whh (+WpH)
__global__ __launch_bounds__(256) void pack_whh(const float* __restrict__ Whf,
                                                const float* __restrict__ Whb,
                                                const float* __restrict__ Wp,
                                                uint4* __restrict__ WT,
                                                unsigned int* __restrict__ WpH) {
  if (blockIdx.x == 256) {   // WpH: [12][256] packed f16 pairs of Wp[12][512]
    for (int it = 0; it < 12; ++it) {
      int idx = it * 256 + threadIdx.x;
      int k = idx >> 8, cc = idx & 255;
      WpH[idx] = pkh(Wp[(size_t)k * 512 + 2 * cc], Wp[(size_t)k * 512 + 2 * cc + 1]);
    }
    return;
  }
  int gid = blockIdx.x * 256 + threadIdx.x;      // 2*128*256 = 65536
  int d = gid >> 15;
  int rem = gid & 32767;
  int kk = rem >> 8, j = rem & 255;
  const float* W = d ? Whb : Whf;
  int k0 = kk * 2;
  uint4 o;
  o.x = pkh(W[(size_t)j * 256 + k0],         W[(size_t)j * 256 + k0 + 1]);
  o.y = pkh(W[(size_t)(j + 256) * 256 + k0], W[(size_t)(j + 256) * 256 + k0 + 1]);
  o.z = pkh(W[(size_t)(j + 512) * 256 + k0], W[(size_t)(j + 512) * 256 + k0 + 1]);
  o.w = pkh(W[(size_t)(j + 768) * 256 + k0], W[(size_t)(j + 768) * 256 + k0 + 1]);
  WT[gid] = o;
}

// ---------------------------------------------------------------- gemm_x (MFMA)
// (unchanged from round 13, incl. XCD swizzle)
__global__ __launch_bounds__(256) void gemm_x(const int* __restrict__ sent,
                                              const float* __restrict__ emb,
                                              const float* __restrict__ Wf,
                                              const float* __restrict__ Wb,
                                              const float* __restrict__ bihf,
                                              const float* __restrict__ bhhf,
                                              const float* __restrict__ bihb,
                                              const float* __restrict__ bhhb,
                                              u16* __restrict__ X4) {
  __shared__ _Float16 A_lds[128][40];
  __shared__ _Float16 B_lds[64][40];
  __shared__ int tok[128];
  __shared__ u16 Xs[128][80];
  int tid = threadIdx.x;
  int lin = blockIdx.y * 32 + blockIdx.x;
  int swz = (lin & 7) * 512 + (lin >> 3);
  int in = swz & 31;                   // 0..31
  int im = swz >> 5;                   // 0..127
  int d = in >> 4, j0 = (in & 15) * 16;
  if (tid < 128) tok[tid] = sent[im * 128 + tid];

  int w = tid >> 6, l = tid & 63;
  int lrow = l & 15, lk = l >> 4;
  f32x4 acc[2][4];
#pragma unroll
  for (int mt = 0; mt < 2; ++mt)
#pragma unroll
    for (int nt = 0; nt < 4; ++nt) acc[mt][nt] = (f32x4)0.0f;

  int arow = tid >> 1, akh = tid & 1;
  int brow = tid & 63, bkq = tid >> 6;
  int r_w = ((brow >> 4) << 8) + j0 + (brow & 15);   // gate*256 + j
  const float* wrow = (d ? Wb : Wf) + (size_t)r_w * 256;

  for (int kc = 0; kc < 8; ++kc) {
    int k0 = kc * 32;
    __syncthreads();
    {
      const float* ap = emb + (size_t)tok[arow] * 256 + k0 + akh * 16;
#pragma unroll
      for (int q = 0; q < 2; ++q) {
        float4 v0 = *(const float4*)(ap + q * 8);
        float4 v1 = *(const float4*)(ap + q * 8 + 4);
        uint4 pk;
        pk.x = pkh(v0.x, v0.y); pk.y = pkh(v0.z, v0.w);
        pk.z = pkh(v1.x, v1.y); pk.w = pkh(v1.z, v1.w);
        *(uint4*)&A_lds[arow][akh * 16 + q * 8] = pk;
      }
    }
    {
      float4 v0 = *(const float4*)(wrow + k0 + bkq * 8);
      float4 v1 = *(const float4*)(wrow + k0 + bkq * 8 + 4);
      uint4 pk;
      pk.x = pkh(v0.x, v0.y); pk.y = pkh(v0.z, v0.w);
      pk.z = pkh(v1.x, v1.y); pk.w = pkh(v1.z, v1.w);
      *(uint4*)&B_lds[brow][bkq * 8] = pk;
    }
    __syncthreads();
    half8 af[2], bf[4];
#pragma unroll
    for (int mt = 0; mt < 2; ++mt)
      af[mt] = *(const half8*)&A_lds[w * 32 + mt * 16 + lrow][lk * 8];
#pragma unroll
    for (int nt = 0; nt < 4; ++nt)
      bf[nt] = *(const half8*)&B_lds[nt * 16 + lrow][lk * 8];
#pragma unroll
    for (int mt = 0; mt < 2; ++mt)
#pragma unroll
      for (int nt = 0; nt < 4; ++nt)
        acc[mt][nt] = __builtin_amdgcn_mfma_f32_16x16x32_f16(af[mt], bf[nt], acc[mt][nt], 0, 0, 0);
  }
  float bias[4];
#pragma unroll
  for (int nt = 0; nt < 4; ++nt) {
    int rr = nt * 256 + j0 + lrow;
    bias[nt] = d ? (bihb[rr] + bhhb[rr]) : (bihf[rr] + bhhf[rr]);
  }
  __syncthreads();
#pragma unroll
  for (int mt = 0; mt < 2; ++mt)
#pragma unroll
    for (int r = 0; r < 4; ++r) {
      int row = w * 32 + mt * 16 + lk * 4 + r;
      uint2 pk;
      pk.x = (unsigned int)f2b(acc[mt][0][r] + bias[0]) |
             ((unsigned int)f2b(acc[mt][1][r] + bias[1]) << 16);
      pk.y = (unsigned int)f2b(acc[mt][2][r] + bias[2]) |
             ((unsigned int)f2b(acc[mt][3][r] + bias[3]) << 16);
      *(uint2*)&Xs[row][lrow * 4] = pk;
    }
  __syncthreads();
  int frow = tid >> 1, fh = tid & 1;
  int i = im * 128 + frow;
  int bb = i >> 8, tt = i & 255;
  size_t base = (((size_t)d * NT + tt) * NB + bb) * 1024 + (size_t)j0 * 4 + fh * 32;
#pragma unroll
  for (int q = 0; q < 4; ++q)
    *(uint4*)&X4[base + q * 8] = *(const uint4*)&Xs[frow][fh * 32 + q * 8];
}

// ---------------------------------------------------------------- lstm_scan
// 128 blocks x 512 threads = (jj 0..255, g 0..1); 2 waves/SIMD.
// Group g owns kk [g*64, g*64+64): first 8 from a 64 KB LDS slab, 56 from
// registers (224 AGPR, within the 256 cap the unified file absorbed in R14).
// All 128 kk resident; per-step global = X4 read + H write only.
// lgkm-only barriers (no vmcnt drain of the H store).
__global__ __launch_bounds__(512, 2) void lstm_scan(const uint4* __restrict__ WT,
                                                    const ushort4* __restrict__ X4,
                                                    const float* __restrict__ h0,
                                                    const float* __restrict__ c0,
                                                    u16* __restrict__ H) {
  int d = blockIdx.x >> 6, b = blockIdx.x & 63;
  int tid = threadIdx.x;
  int jj = tid & 255, g = tid >> 8;       // g in 0..1
  __shared__ uint4 wlds[2 * KK_SLAB2 * 256];   // 65536 B slab
  __shared__ uint4 h2s4[32];                   // 512 B: 128 packed f16 h pairs
  __shared__ float4 plds[256];                 // 4096 B: g1 partials
  const uint4* Ws = WT + (size_t)d * 32768;    // [kk][j 0..255]
  // slab init: sr in [0,16): gg = sr/8, r = sr%8 -> kk = gg*64 + r
  for (int e = tid; e < 2 * KK_SLAB2 * 256; e += 512) {
    int sr = e >> 8, j2 = e & 255;
    int gg = sr / KK_SLAB2, r = sr - gg * KK_SLAB2;
    wlds[e] = Ws[(size_t)(gg * 64 + r) * 256 + j2];
  }
  // persistent register weights: kk = g*64 + 8 + r  (static unroll)
  uint4 wreg[KK_REG2];
#pragma unroll
  for (int r = 0; r < KK_REG2; ++r)
    wreg[r] = Ws[(size_t)(g * 64 + KK_SLAB2 + r) * 256 + jj];
  float c = 0.f;
  if (g == 0) c = c0[((size_t)d * NB + b) * 256 + jj];
  if (tid < 256) ((u16*)h2s4)[tid] = f2h(h0[((size_t)d * NB + b) * 256 + tid]);
  __syncthreads();
  for (int s = 0; s < NT; ++s) {
    int t = d ? (NT - 1 - s) : s;
    ushort4 xg = make_ushort4(0, 0, 0, 0);
    if (g == 0) xg = X4[(((size_t)d * NT + t) * NB + b) * 256 + jj];  // used at end
    float ai = 0.f, af = 0.f, ag = 0.f, ao = 0.f;
#pragma unroll
    for (int q = 0; q < 16; ++q) {
      uint4 h4 = h2s4[g * 16 + q];                 // uniform -> broadcast b128
      unsigned int hp[4] = {h4.x, h4.y, h4.z, h4.w};
#pragma unroll
      for (int e = 0; e < 4; ++e) {
        int kkl = q * 4 + e;                       // compile-time constant
        uint4 wv;
        if (kkl < KK_SLAB2) wv = wlds[((g * KK_SLAB2 + kkl) << 8) | jj];
        else                wv = wreg[kkl - KK_SLAB2];
        ai = dot2h(wv.x, hp[e], ai); af = dot2h(wv.y, hp[e], af);
        ag = dot2h(wv.z, hp[e], ag); ao = dot2h(wv.w, hp[e], ao);
      }
    }
    if (g) plds[jj] = make_float4(ai, af, ag, ao);
    barrier_lds();                     // partials visible; h2s4 reads done
    if (g == 0) {
      float4 p0 = plds[jj];
      ai += p0.x + b2f(xg.x);
      af += p0.y + b2f(xg.y);
      ag += p0.z + b2f(xg.z);
      ao += p0.w + b2f(xg.w);
      float ii = fsig(ai), ff = fsig(af), gg2 = ftanh(ag), oo = fsig(ao);
      c = ff * c + ii * gg2;
      float h = oo * ftanh(c);
      u16 hu = f2h(h);
      ((u16*)h2s4)[jj] = hu;
      H[(((size_t)d * NB + b) * NT + t) * 256 + jj] = hu;  // fire-and-forget
    }
    barrier_lds();                     // h2s4 updated before next step
  }
}

// ---------------------------------------------------------------- feats
// (unchanged from round 13)
__global__ __launch_bounds__(384) void feats_kernel(const u16* __restrict__ H,
                                                    const unsigned int* __restrict__ WpH,
                                                    const float* __restrict__ bp,
                                                    float* __restrict__ FT) {
  __shared__ uint4 hbuf[32][65];
  __shared__ uint4 wbuf[64][12];
  int tid = threadIdx.x;
  int i0 = blockIdx.x * 32;
  for (int idx = tid; idx < 768; idx += 384) {
    int it = idx / 12, k = idx - it * 12;
    wbuf[it][k] = ((const uint4*)WpH)[k * 64 + it];
  }
  for (int idx = tid; idx < 2048; idx += 384) {
    int row = idx >> 6, c4 = idx & 63;
    int i = i0 + row;
    int b = i >> 8, t = i & 255;
    int dd = c4 >> 5, cc = c4 & 31;
    const uint4* hpg = (const uint4*)(H + (((size_t)dd * NB + b) * NT + t) * 256);
    hbuf[row][c4] = hpg[cc];
  }
  __syncthreads();
  int row = tid / 12, k = tid - row * 12;
  float s0 = 0.f, s1 = 0.f, s2 = 0.f, s3 = 0.f;
#pragma unroll 8
  for (int it = 0; it < 64; ++it) {
    uint4 h4 = hbuf[row][it];
    uint4 w4 = wbuf[it][k];
    s0 = dot2h(h4.x, w4.x, s0); s1 = dot2h(h4.y, w4.y, s1);
    s2 = dot2h(h4.z, w4.z, s2); s3 = dot2h(h4.w, w4.w, s3);
  }
  int i = i0 + row;
  FT[(size_t)i * NKTAG + k] = (s0 + s1) + (s2 + s3) + bp[k];
}

// ---------------------------------------------------------------- viterbi
// (unchanged from round 13, incl. FT prefetch)
__global__ __launch_bounds__(64) void viterbi_kernel(const float* __restrict__ FT,
                                                     const float* __restrict__ trans,
                                                     const int* __restrict__ sent,
                                                     float* __restrict__ out) {
  int b = blockIdx.x, tid = threadIdx.x;
  __shared__ float trans_s[12][12];
  __shared__ float s_s[12];
  __shared__ unsigned char bp_s[256][12];
  __shared__ int path_s[256];
  for (int idx = tid; idx < 144; idx += 64) trans_s[idx / 12][idx % 12] = trans[idx];
  int cnt = 0;
#pragma unroll
  for (int q = 0; q < 4; ++q) cnt += (sent[b * NT + q * 64 + tid] > 0) ? 1 : 0;
  for (int off = 32; off; off >>= 1) cnt += __shfl_down(cnt, off);
  int len = __shfl(cnt, 0);
  if (tid < 12) s_s[tid] = (tid == START_TAG) ? 0.f : -10000.f;
  float f_next = (tid < 12) ? FT[((size_t)b * NT) * NKTAG + tid] : 0.f;
  __syncthreads();
  for (int t = 0; t < NT; ++t) {
    float best = 0.f, f = f_next;
    int barg = 0;
    if (t + 1 < NT && tid < 12)
      f_next = FT[((size_t)b * NT + t + 1) * NKTAG + tid];  // prefetch, state-indep
    if (tid < 12) {
      best = s_s[0] + trans_s[tid][0];
      barg = 0;
#pragma unroll
      for (int fr = 1; fr < 12; ++fr) {
        float v = s_s[fr] + trans_s[tid][fr];
        if (v > best) { best = v; barg = fr; }  // strict > keeps first (jnp.argmax)
      }
    }
    __syncthreads();
    if (tid < 12) {
      s_s[tid] = best + f;
      bp_s[t][tid] = (unsigned char)barg;
    }
    __syncthreads();
  }
  if (tid == 0) {
    float bs = s_s[0];
    int bt = 0;
    for (int k = 1; k < 12; ++k)
      if (s_s[k] > bs) { bs = s_s[k]; bt = k; }
    out[NB * NT + b] = bs;
    int x = bt;
    for (int tt = NT - 1; tt >= 0; --tt) {
      path_s[tt] = x;
      int nxt = bp_s[tt][x];
      if (tt < len) x = nxt;
    }
  }
  __syncthreads();
#pragma unroll
  for (int q = 0; q < 4; ++q) {
    int t = q * 64 + tid;
    out[b * NT + t] = (t < len) ? (float)path_s[t] : -1.0f;
  }
}

// ---------------------------------------------------------------- launch
extern "C" void kernel_launch(void* const* d_in, const int* in_sizes, int n_in,
                              void* d_out, int out_size, void* d_ws, size_t ws_size,
                              hipStream_t stream) {
  (void)in_sizes; (void)n_in; (void)out_size; (void)ws_size;
  const int*   sent  = (const int*)d_in[0];
  const float* emb   = (const float*)d_in[2];
  const float* Wih_f = (const float*)d_in[3];
  const float* Whh_f = (const float*)d_in[4];
  const float* bih_f = (const float*)d_in[5];
  const float* bhh_f = (const float*)d_in[6];
  const float* Wih_b = (const float*)d_in[7];
  const float* Whh_b = (const float*)d_in[8];
  const float* bih_b = (const float*)d_in[9];
  const float* bhh_b = (const float*)d_in[10];
  const float* Wp    = (const float*)d_in[11];
  const float* bp    = (const float*)d_in[12];
  const float* trans = (const float*)d_in[13];
  const float* h0    = (const float*)d_in[14];
  const float* c0    = (const float*)d_in[15];
  float* out = (float*)d_out;

  char* w = (char*)d_ws;
  u16*   X4  = (u16*)w;                                      // 67108864 B
  uint4* WTH = (uint4*)(w + 67108864);                       //  1048576 B
  float* FT  = (float*)(w + 68157440);                       //   786432 B
  unsigned int* WpH = (unsigned int*)(w + 68943872);         //    12288 B
  u16*   H   = (u16*)(w + 68956160);                         // 16777216 B

  pack_whh<<<dim3(257), dim3(256), 0, stream>>>(Whh_f, Whh_b, Wp, WTH, WpH);
  gemm_x<<<dim3(32, 128), dim3(256), 0, stream>>>(sent, emb, Wih_f, Wih_b,
                                                  bih_f, bhh_f, bih_b, bhh_b, X4);
  lstm_scan<<<dim3(128), dim3(512), 0, stream>>>(WTH, (const ushort4*)X4, h0, c0, H);
  feats_kernel<<<dim3(512), dim3(384), 0, stream>>>(H, WpH, bp, FT);
  viterbi_kernel<<<dim3(64), dim3(64), 0, stream>>>(FT, trans, sent, out);
}

// Round 18
// 550.375 us; speedup vs baseline: 1.9328x; 1.0157x over previous
//
#include <hip/hip_runtime.h>

// BiLSTM-CRF on MI355X — round 18: R17 with the epilogue-flush bug fixed
// (q<4 -> q<8: each (row,half) must flush 64 u16 = 8 uint4; R17 left columns
// 32..63 / 96..127 unwritten -> absmax 40). All else identical to R17:
//  * gemm_x: 128x128 tile (2048 blocks), XCD swizzle, pack fused (2048..2304)
//  * lstm_scan: byte-identical R16 control (410us structural floor)
//
// ws layout: X4 (67108864) | WTH (1048576) | FT (786432) | WpH (12288) |
//            H u16 (16777216)  = 85.7 MB total.
// Output (float32): d_out[0:16384] = paths (floats, -1 past length), [16384:16448] = best_score.

#define NB 64
#define NT 256
#define NKTAG 12
#define START_TAG 10
#define KK_SLAB2 8    // per-group LDS-slab kk (16 total = 65536 B)
#define KK_REG2 56    // per-group register kk (56 x uint4 = 224 regs)

typedef unsigned short u16;
typedef _Float16 half2v __attribute__((ext_vector_type(2)));
typedef _Float16 half8 __attribute__((ext_vector_type(8)));
typedef float f32x4 __attribute__((ext_vector_type(4)));

__device__ __forceinline__ float b2f(u16 u) {
  union { unsigned int i; float f; } v; v.i = ((unsigned int)u) << 16; return v.f;
}
__device__ __forceinline__ u16 f2b(float f) {
  union { float f; unsigned int i; } v; v.f = f;
  unsigned int r = v.i + 0x7FFFu + ((v.i >> 16) & 1u);
  return (u16)(r >> 16);
}
__device__ __forceinline__ u16 f2h(float f) {
  union { _Float16 h; u16 u; } v; v.h = (_Float16)f; return v.u;
}
__device__ __forceinline__ unsigned int pkh(float x, float y) {
  return (unsigned int)f2h(x) | ((unsigned int)f2h(y) << 16);
}
__device__ __forceinline__ float fsig(float x) { return 1.0f / (1.0f + __expf(-x)); }
__device__ __forceinline__ float ftanh(float x) { return 2.0f / (1.0f + __expf(-2.0f * x)) - 1.0f; }

__device__ __forceinline__ float dot2h(unsigned int a, unsigned int b, float c) {
#if __has_builtin(__builtin_amdgcn_fdot2)
  union { unsigned int u; half2v h; } va, vb;
  va.u = a; vb.u = b;
  return __builtin_amdgcn_fdot2(va.h, vb.h, c, false);
#else
  float d;
  asm("v_dot2_f32_f16 %0, %1, %2, %3" : "=v"(d) : "v"(a), "v"(b), "v"(c));
  return d;
#endif
}

// LDS-only barrier (scan): wait LDS ops, then raw s_barrier.
__device__ __forceinline__ void barrier_lds() {
  asm volatile("s_waitcnt lgkmcnt(0)" ::: "memory");
  __builtin_amdgcn_s_barrier();
}

// ---------------------------------------------------------------- gemm_x (+fused pack)
// Blocks 0..2047: GEMM, 128(M) x 128(N) tile. lin -> XCD swizzle -> (im, in):
// im 0..127 (M tile: one b-half, 128 consecutive t), in 0..15: d = in>>3,
// j0 = (in&7)*32 (N tile = 32 j x 4 gates). K = 8 chunks x 32.
// Blocks 2048..2303: Whh f16 packing (WTH). Block 2304: WpH.
__global__ __launch_bounds__(256, 2) void gemm_x(const int* __restrict__ sent,
                                                 const float* __restrict__ emb,
                                                 const float* __restrict__ Wf,
                                                 const float* __restrict__ Wb,
                                                 const float* __restrict__ bihf,
                                                 const float* __restrict__ bhhf,
                                                 const float* __restrict__ bihb,
                                                 const float* __restrict__ bhhb,
                                                 const float* __restrict__ Whf,
                                                 const float* __restrict__ Whb,
                                                 const float* __restrict__ Wp,
                                                 uint4* __restrict__ WT,
                                                 unsigned int* __restrict__ WpH,
                                                 u16* __restrict__ X4) {
  int tid = threadIdx.x;
  if (blockIdx.x >= 2048) {
    int pb = blockIdx.x - 2048;
    if (pb == 256) {   // WpH: [12][256] packed f16 pairs of Wp[12][512]
      for (int it = 0; it < 12; ++it) {
        int idx = it * 256 + tid;
        int k = idx >> 8, cc = idx & 255;
        WpH[idx] = pkh(Wp[(size_t)k * 512 + 2 * cc], Wp[(size_t)k * 512 + 2 * cc + 1]);
      }
      return;
    }
    int gid = pb * 256 + tid;      // 2*128*256 = 65536
    int d = gid >> 15;
    int rem = gid & 32767;
    int kk = rem >> 8, j = rem & 255;
    const float* W = d ? Whb : Whf;
    int k0 = kk * 2;
    uint4 o;
    o.x = pkh(W[(size_t)j * 256 + k0],         W[(size_t)j * 256 + k0 + 1]);
    o.y = pkh(W[(size_t)(j + 256) * 256 + k0], W[(size_t)(j + 256) * 256 + k0 + 1]);
    o.z = pkh(W[(size_t)(j + 512) * 256 + k0], W[(size_t)(j + 512) * 256 + k0 + 1]);
    o.w = pkh(W[(size_t)(j + 768) * 256 + k0], W[(size_t)(j + 768) * 256 + k0 + 1]);
    WT[gid] = o;
    return;
  }
  __shared__ _Float16 A_lds[128][40];
  __shared__ _Float16 B_lds[128][40];
  __shared__ int tok[128];
  __shared__ u16 Xs[128][136];         // row stride 272 B (16B-aligned)
  int lin = blockIdx.x;
  int swz = (lin & 7) * 256 + (lin >> 3);   // bijective: 2048 = 8*256
  int in = swz & 15;                   // 0..15
  int im = swz >> 4;                   // 0..127
  int d = in >> 3, j0 = (in & 7) * 32;
  if (tid < 128) tok[tid] = sent[im * 128 + tid];

  int w = tid >> 6, l = tid & 63;
  int lrow = l & 15, lk = l >> 4;
  f32x4 acc[2][8];
#pragma unroll
  for (int mt = 0; mt < 2; ++mt)
#pragma unroll
    for (int nt = 0; nt < 8; ++nt) acc[mt][nt] = (f32x4)0.0f;

  int arow = tid >> 1, akh = tid & 1;          // A: 128 rows x 2 k-halves
  int brow = tid & 127, bhalf = tid >> 7;      // B: 128 rows x 2 k-halves
  int r_w = ((brow >> 5) << 8) + j0 + (brow & 31);   // gate*256 + j
  const float* wrow = (d ? Wb : Wf) + (size_t)r_w * 256;

  for (int kc = 0; kc < 8; ++kc) {
    int k0 = kc * 32;
    __syncthreads();   // covers tok on first iteration
    {
      const float* ap = emb + (size_t)tok[arow] * 256 + k0 + akh * 16;
#pragma unroll
      for (int q = 0; q < 2; ++q) {
        float4 v0 = *(const float4*)(ap + q * 8);
        float4 v1 = *(const float4*)(ap + q * 8 + 4);
        uint4 pk;
        pk.x = pkh(v0.x, v0.y); pk.y = pkh(v0.z, v0.w);
        pk.z = pkh(v1.x, v1.y); pk.w = pkh(v1.z, v1.w);
        *(uint4*)&A_lds[arow][akh * 16 + q * 8] = pk;
      }
    }
    {
      const float* bp_ = wrow + k0 + bhalf * 16;
#pragma unroll
      for (int q = 0; q < 2; ++q) {
        float4 v0 = *(const float4*)(bp_ + q * 8);
        float4 v1 = *(const float4*)(bp_ + q * 8 + 4);
        uint4 pk;
        pk.x = pkh(v0.x, v0.y); pk.y = pkh(v0.z, v0.w);
        pk.z = pkh(v1.x, v1.y); pk.w = pkh(v1.z, v1.w);
        *(uint4*)&B_lds[brow][bhalf * 16 + q * 8] = pk;
      }
    }
    __syncthreads();
    half8 af[2], bf[8];
#pragma unroll
    for (int mt = 0; mt < 2; ++mt)
      af[mt] = *(const half8*)&A_lds[w * 32 + mt * 16 + lrow][lk * 8];
#pragma unroll
    for (int nt = 0; nt < 8; ++nt)
      bf[nt] = *(const half8*)&B_lds[nt * 16 + lrow][lk * 8];
#pragma unroll
    for (int mt = 0; mt < 2; ++mt)
#pragma unroll
      for (int nt = 0; nt < 8; ++nt)
        acc[mt][nt] = __builtin_amdgcn_mfma_f32_16x16x32_f16(af[mt], bf[nt], acc[mt][nt], 0, 0, 0);
  }
  // epilogue: bias, pack gates, stage to Xs, dense flush.
  // n = nt*16+lrow: gate = n>>5, jloc = n&31. jloc==lrow from nt{0,2,4,6};
  // jloc==16+lrow from nt{1,3,5,7}.
  float bias[8];
#pragma unroll
  for (int nt = 0; nt < 8; ++nt) {
    int n = nt * 16 + lrow;
    int rr = ((n >> 5) << 8) + j0 + (n & 31);
    bias[nt] = d ? (bihb[rr] + bhhb[rr]) : (bihf[rr] + bhhf[rr]);
  }
  __syncthreads();  // A/B_lds done; Xs phase
#pragma unroll
  for (int mt = 0; mt < 2; ++mt)
#pragma unroll
    for (int r = 0; r < 4; ++r) {
      int row = w * 32 + mt * 16 + lk * 4 + r;
      uint2 p0, p1;
      p0.x = (unsigned int)f2b(acc[mt][0][r] + bias[0]) |
             ((unsigned int)f2b(acc[mt][2][r] + bias[2]) << 16);
      p0.y = (unsigned int)f2b(acc[mt][4][r] + bias[4]) |
             ((unsigned int)f2b(acc[mt][6][r] + bias[6]) << 16);
      p1.x = (unsigned int)f2b(acc[mt][1][r] + bias[1]) |
             ((unsigned int)f2b(acc[mt][3][r] + bias[3]) << 16);
      p1.y = (unsigned int)f2b(acc[mt][5][r] + bias[5]) |
             ((unsigned int)f2b(acc[mt][7][r] + bias[7]) << 16);
      *(uint2*)&Xs[row][lrow * 4] = p0;            // jloc = lrow
      *(uint2*)&Xs[row][(16 + lrow) * 4] = p1;     // jloc = 16+lrow
    }
  __syncthreads();
  int frow = tid >> 1, fh = tid & 1;
  int i = im * 128 + frow;
  int bb = i >> 8, tt = i & 255;
  size_t base = (((size_t)d * NT + tt) * NB + bb) * 1024 + (size_t)j0 * 4 + fh * 64;
#pragma unroll
  for (int q = 0; q < 8; ++q)     // FIX: 8 uint4 = 64 u16 per (row, half)
    *(uint4*)&X4[base + q * 8] = *(const uint4*)&Xs[frow][fh * 64 + q * 8];
}

// ---------------------------------------------------------------- lstm_scan
// (byte-identical R16 — the 410us control)
__global__ __launch_bounds__(512, 2) void lstm_scan(const uint4* __restrict__ WT,
                                                    const ushort4* __restrict__ X4,
                                                    const float* __restrict__ h0,
                                                    const float* __restrict__ c0,
                                                    u16* __restrict__ H) {
  int d = blockIdx.x >> 6, b = blockIdx.x & 63;
  int tid = threadIdx.x;
  int jj = tid & 255, g = tid >> 8;       // g in 0..1
  __shared__ uint4 wlds[2 * KK_SLAB2 * 256];   // 65536 B slab
  __shared__ uint4 h2s4[32];                   // 512 B: 128 packed f16 h pairs
  __shared__ float4 plds[256];                 // 4096 B: g1 partials
  const uint4* Ws = WT + (size_t)d * 32768;    // [kk][j 0..255]
  for (int e = tid; e < 2 * KK_SLAB2 * 256; e += 512) {
    int sr = e >> 8, j2 = e & 255;
    int gg = sr / KK_SLAB2, r = sr - gg * KK_SLAB2;
    wlds[e] = Ws[(size_t)(gg * 64 + r) * 256 + j2];
  }
  uint4 wreg[KK_REG2];
#pragma unroll
  for (int r = 0; r < KK_REG2; ++r)
    wreg[r] = Ws[(size_t)(g * 64 + KK_SLAB2 + r) * 256 + jj];
  float c = 0.f;
  if (g == 0) c = c0[((size_t)d * NB + b) * 256 + jj];
  if (tid < 256) ((u16*)h2s4)[tid] = f2h(h0[((size_t)d * NB + b) * 256 + tid]);
  __syncthreads();
  for (int s = 0; s < NT; ++s) {
    int t = d ? (NT - 1 - s) : s;
    ushort4 xg = make_ushort4(0, 0, 0, 0);
    if (g == 0) xg = X4[(((size_t)d * NT + t) * NB + b) * 256 + jj];  // used at end
    float ai = 0.f, af = 0.f, ag = 0.f, ao = 0.f;
#pragma unroll
    for (int q = 0; q < 16; ++q) {
      uint4 h4 = h2s4[g * 16 + q];                 // uniform -> broadcast b128
      unsigned int hp[4] = {h4.x, h4.y, h4.z, h4.w};
#pragma unroll
      for (int e = 0; e < 4; ++e) {
        int kkl = q * 4 + e;                       // compile-time constant
        uint4 wv;
        if (kkl < KK_SLAB2) wv = wlds[((g * KK_SLAB2 + kkl) << 8) | jj];
        else                wv = wreg[kkl - KK_SLAB2];
        ai = dot2h(wv.x, hp[e], ai); af = dot2h(wv.y, hp[e], af);
        ag = dot2h(wv.z, hp[e], ag); ao = dot2h(wv.w, hp[e], ao);
      }
    }
    if (g) plds[jj] = make_float4(ai, af, ag, ao);
    barrier_lds();                     // partials visible; h2s4 reads done
    if (g == 0) {
      float4 p0 = plds[jj];
      ai += p0.x + b2f(xg.x);
      af += p0.y + b2f(xg.y);
      ag += p0.z + b2f(xg.z);
      ao += p0.w + b2f(xg.w);
      float ii = fsig(ai), ff = fsig(af), gg2 = ftanh(ag), oo = fsig(ao);
      c = ff * c + ii * gg2;
      float h = oo * ftanh(c);
      u16 hu = f2h(h);
      ((u16*)h2s4)[jj] = hu;
      H[(((size_t)d * NB + b) * NT + t) * 256 + jj] = hu;  // fire-and-forget
    }
    barrier_lds();                     // h2s4 updated before next step
  }
}

// ---------------------------------------------------------------- feats
// (unchanged from round 13)
__global__ __launch_bounds__(384) void feats_kernel(const u16* __restrict__ H,
                                                    const unsigned int* __restrict__ WpH,
                                                    const float* __restrict__ bp,
                                                    float* __restrict__ FT) {
  __shared__ uint4 hbuf[32][65];
  __shared__ uint4 wbuf[64][12];
  int tid = threadIdx.x;
  int i0 = blockIdx.x * 32;
  for (int idx = tid; idx < 768; idx += 384) {
    int it = idx / 12, k = idx - it * 12;
    wbuf[it][k] = ((const uint4*)WpH)[k * 64 + it];
  }
  for (int idx = tid; idx < 2048; idx += 384) {
    int row = idx >> 6, c4 = idx & 63;
    int i = i0 + row;
    int b = i >> 8, t = i & 255;
    int dd = c4 >> 5, cc = c4 & 31;
    const uint4* hpg = (const uint4*)(H + (((size_t)dd * NB + b) * NT + t) * 256);
    hbuf[row][c4] = hpg[cc];
  }
  __syncthreads();
  int row = tid / 12, k = tid - row * 12;
  float s0 = 0.f, s1 = 0.f, s2 = 0.f, s3 = 0.f;
#pragma unroll 8
  for (int it = 0; it < 64; ++it) {
    uint4 h4 = hbuf[row][it];
    uint4 w4 = wbuf[it][k];
    s0 = dot2h(h4.x, w4.x, s0); s1 = dot2h(h4.y, w4.y, s1);
    s2 = dot2h(h4.z, w4.z, s2); s3 = dot2h(h4.w, w4.w, s3);
  }
  int i = i0 + row;
  FT[(size_t)i * NKTAG + k] = (s0 + s1) + (s2 + s3) + bp[k];
}

// ---------------------------------------------------------------- viterbi
// (unchanged from round 13, incl. FT prefetch)
__global__ __launch_bounds__(64) void viterbi_kernel(const float* __restrict__ FT,
                                                     const float* __restrict__ trans,
                                                     const int* __restrict__ sent,
                                                     float* __restrict__ out) {
  int b = blockIdx.x, tid = threadIdx.x;
  __shared__ float trans_s[12][12];
  __shared__ float s_s[12];
  __shared__ unsigned char bp_s[256][12];
  __shared__ int path_s[256];
  for (int idx = tid; idx < 144; idx += 64) trans_s[idx / 12][idx % 12] = trans[idx];
  int cnt = 0;
#pragma unroll
  for (int q = 0; q < 4; ++q) cnt += (sent[b * NT + q * 64 + tid] > 0) ? 1 : 0;
  for (int off = 32; off; off >>= 1) cnt += __shfl_down(cnt, off);
  int len = __shfl(cnt, 0);
  if (tid < 12) s_s[tid] = (tid == START_TAG) ? 0.f : -10000.f;
  float f_next = (tid < 12) ? FT[((size_t)b * NT) * NKTAG + tid] : 0.f;
  __syncthreads();
  for (int t = 0; t < NT; ++t) {
    float best = 0.f, f = f_next;
    int barg = 0;
    if (t + 1 < NT && tid < 12)
      f_next = FT[((size_t)b * NT + t + 1) * NKTAG + tid];  // prefetch, state-indep
    if (tid < 12) {
      best = s_s[0] + trans_s[tid][0];
      barg = 0;
#pragma unroll
      for (int fr = 1; fr < 12; ++fr) {
        float v = s_s[fr] + trans_s[tid][fr];
        if (v > best) { best = v; barg = fr; }  // strict > keeps first (jnp.argmax)
      }
    }
    __syncthreads();
    if (tid < 12) {
      s_s[tid] = best + f;
      bp_s[t][tid] = (unsigned char)barg;
    }
    __syncthreads();
  }
  if (tid == 0) {
    float bs = s_s[0];
    int bt = 0;
    for (int k = 1; k < 12; ++k)
      if (s_s[k] > bs) { bs = s_s[k]; bt = k; }
    out[NB * NT + b] = bs;
    int x = bt;
    for (int tt = NT - 1; tt >= 0; --tt) {
      path_s[tt] = x;
      int nxt = bp_s[tt][x];
      if (tt < len) x = nxt;
    }
  }
  __syncthreads();
#pragma unroll
  for (int q = 0; q < 4; ++q) {
    int t = q * 64 + tid;
    out[b * NT + t] = (t < len) ? (float)path_s[t] : -1.0f;
  }
}

// ---------------------------------------------------------------- launch
extern "C" void kernel_launch(void* const* d_in, const int* in_sizes, int n_in,
                              void* d_out, int out_size, void* d_ws, size_t ws_size,
                              hipStream_t stream) {
  (void)in_sizes; (void)n_in; (void)out_size; (void)ws_size;
  const int*   sent  = (const int*)d_in[0];
  const float* emb   = (const float*)d_in[2];
  const float* Wih_f = (const float*)d_in[3];
  const float* Whh_f = (const float*)d_in[4];
  const float* bih_f = (const float*)d_in[5];
  const float* bhh_f = (const float*)d_in[6];
  const float* Wih_b = (const float*)d_in[7];
  const float* Whh_b = (const float*)d_in[8];
  const float* bih_b = (const float*)d_in[9];
  const float* bhh_b = (const float*)d_in[10];
  const float* Wp    = (const float*)d_in[11];
  const float* bp    = (const float*)d_in[12];
  const float* trans = (const float*)d_in[13];
  const float* h0    = (const float*)d_in[14];
  const float* c0    = (const float*)d_in[15];
  float* out = (float*)d_out;

  char* w = (char*)d_ws;
  u16*   X4  = (u16*)w;                                      // 67108864 B
  uint4* WTH = (uint4*)(w + 67108864);                       //  1048576 B
  float* FT  = (float*)(w + 68157440);                       //   786432 B
  unsigned int* WpH = (unsigned int*)(w + 68943872);         //    12288 B
  u16*   H   = (u16*)(w + 68956160);                         // 16777216 B

  gemm_x<<<dim3(2305), dim3(256), 0, stream>>>(sent, emb, Wih_f, Wih_b,
                                               bih_f, bhh_f, bih_b, bhh_b,
                                               Whh_f, Whh_b, Wp, WTH, WpH, X4);
  lstm_scan<<<dim3(128), dim3(512), 0, stream>>>(WTH, (const ushort4*)X4, h0, c0, H);
  feats_kernel<<<dim3(512), dim3(384), 0, stream>>>(H, WpH, bp, FT);
  viterbi_kernel<<<dim3(64), dim3(64), 0, stream>>>(FT, trans, sent, out);
}